// Round 2
// baseline (274.339 us; speedup 1.0000x reference)
//
#include <hip/hip_runtime.h>
#include <hip/hip_bf16.h>

#define B_SZ 4
#define T_SEQ 1024
#define DM 128
#define ED_ 256
#define NS 64

// workspace layout (float elements). Total = 5,996,544 floats = 24.0 MB (< accepted 25.6 MB).
// delta/xs merged into dxpack {delta, xs} float2; Bm/Cm merged into bcpack {B, C} float2.
#define OFF_Z      0u         /* 524288  f32  z (residual, read by K6)            */
#define OFF_ZG     524288u    /* 1048576 f32  gate (k2 -> k6)                     */
#define OFF_XSR    1572864u   /* 1048576 f32  conv input (k2 -> k4b)              */
#define OFF_WC     2621440u   /* 98304   f32  combined x_proj/dt weight (384x256) */
#define OFF_YR     2719744u   /* 1048576 f32  raw scan output (k5 -> k6)          */
#define OFF_DPX    3768320u   /* 2097152 f32  {delta, xs} pairs (k4b -> k5,k6)    */
#define OFF_BC     5865472u   /* 131072  f32  {B, C} pairs (k4b -> k5)            */

__device__ __forceinline__ float sigmoidf_(float x){ return 1.f/(1.f+__expf(-x)); }
__device__ __forceinline__ float exp2_(float x){ return __builtin_amdgcn_exp2f(x); }

// Fused DPP add: p += dpp(p) in ONE instruction (v_add_f32_dpp).
// bound_ctrl:0 => lanes with invalid source read 0 (identity for add).
#define DPPR(p, ctl) asm("v_add_f32_dpp %0, %0, %0 " ctl " row_mask:0xf bank_mask:0xf bound_ctrl:0" : "+v"(p))

// K2f: blocks 0..511: fused [z = zseq+aux@auxW.T+auxb ; zn=RMSNorm(z)*rms_w] -> LDS,
//      then xz = zn @ in_proj_W.T -> xsr | zg. 8 rows/block.
//      blocks 512..895: build combined weight Wc.
__global__ __launch_bounds__(256) void k2_fused(const float* zseq, const float* aux, const float* auxW,
                                                const float* auxb, const float* rmsw, const float* W,
                                                const float* xprojW, const float* dtW,
                                                float* z, float* xsr, float* zg, float* Wc){
  if (blockIdx.x >= 512){
    int r = blockIdx.x - 512; int k = threadIdx.x;
    float v;
    if (r < 256){
      v = 0.f;
      #pragma unroll
      for (int j=0;j<8;j++) v += dtW[r*8+j] * xprojW[j*256+k];
    } else {
      v = xprojW[(8 + r-256)*256 + k];
    }
    Wc[r*256+k] = v;
    return;
  }
  __shared__ float at[128][8];
  int bt0 = blockIdx.x*8; int tid = threadIdx.x;
  {
    int r = tid>>5, l = tid&31;
    int bt = bt0 + r;
    float a0 = aux[bt*3+0], a1 = aux[bt*3+1], a2 = aux[bt*3+2];
    float zv[4]; float ssq = 0.f;
    #pragma unroll
    for (int j=0;j<4;j++){
      int d = l + 32*j;
      float v = zseq[bt*DM+d] + a0*auxW[d*3+0] + a1*auxW[d*3+1] + a2*auxW[d*3+2] + auxb[d];
      zv[j] = v; ssq += v*v;
    }
    #pragma unroll
    for (int m=16;m>=1;m>>=1) ssq += __shfl_xor(ssq, m);
    float rinv = rsqrtf(ssq*(1.f/DM) + 1e-5f);
    #pragma unroll
    for (int j=0;j<4;j++){
      int d = l + 32*j;
      z[bt*DM+d] = zv[j];
      at[d][r] = zv[j]*rinv*rmsw[d];
    }
  }
  __syncthreads();
  float acc0[8], acc1[8];
  #pragma unroll
  for (int r=0;r<8;r++){ acc0[r]=0.f; acc1[r]=0.f; }
  int c0 = tid, c1 = tid+256;
  for (int k=0;k<128;k+=4){
    float4 w0v = *(const float4*)(W + c0*128 + k);
    float4 w1v = *(const float4*)(W + c1*128 + k);
    float w0[4] = {w0v.x, w0v.y, w0v.z, w0v.w};
    float w1[4] = {w1v.x, w1v.y, w1v.z, w1v.w};
    #pragma unroll
    for (int kk=0;kk<4;kk++){
      float a[8];
      *(float4*)&a[0] = *(const float4*)&at[k+kk][0];
      *(float4*)&a[4] = *(const float4*)&at[k+kk][4];
      #pragma unroll
      for (int r=0;r<8;r++){ acc0[r] = fmaf(a[r], w0[kk], acc0[r]); acc1[r] = fmaf(a[r], w1[kk], acc1[r]); }
    }
  }
  #pragma unroll
  for (int r=0;r<8;r++){
    int bt = bt0+r;
    xsr[bt*ED_ + c0] = acc0[r];
    zg [bt*ED_ + c0] = acc1[r];
  }
}

// K4b: staging computes conv(k=4)+bias+SiLU from xsr (LDS only), then
// [delta_pre | B | C] = xs @ Wc.T. Writes PACKED outputs:
//   dxp[bt][e]  = {softplus(delta_pre+dt_b), xs}   (float2)
//   bcp[bt][n]  = {B, C}                            (float2, written as 2 scalars)
__global__ __launch_bounds__(384) void k4b_xproj(const float* xsr, const float* convW, const float* convb,
                                                 const float* Wc, const float* dtb,
                                                 float* dxp, float* bcf){
  __shared__ float at[256][8];
  int bt0 = blockIdx.x*8; int tid = threadIdx.x;
  for (int i=tid;i<2048;i+=384){
    int r=i>>8,k=i&255; int bt=bt0+r; int t = bt & (T_SEQ-1);
    float4 wv = *(const float4*)(convW + k*4);
    float s = convb[k];
    if (t>=3) s += xsr[(bt-3)*ED_+k]*wv.x;
    if (t>=2) s += xsr[(bt-2)*ED_+k]*wv.y;
    if (t>=1) s += xsr[(bt-1)*ED_+k]*wv.z;
    s += xsr[bt*ED_+k]*wv.w;
    at[k][r] = s * sigmoidf_(s);
  }
  __syncthreads();
  float acc[8];
  #pragma unroll
  for (int r=0;r<8;r++) acc[r]=0.f;
  int c = tid;
  for (int k=0;k<256;k+=4){
    float4 wv = *(const float4*)(Wc + c*256 + k);
    float w[4] = {wv.x, wv.y, wv.z, wv.w};
    #pragma unroll
    for (int kk=0;kk<4;kk++){
      float a[8];
      *(float4*)&a[0] = *(const float4*)&at[k+kk][0];
      *(float4*)&a[4] = *(const float4*)&at[k+kk][4];
      #pragma unroll
      for (int r=0;r<8;r++) acc[r] = fmaf(a[r], w[kk], acc[r]);
    }
  }
  if (c < 256){
    float bc = dtb[c];
    #pragma unroll
    for (int r=0;r<8;r++){
      float x = acc[r] + bc;
      float dv = (x > 20.f) ? x : log1pf(__expf(x));
      *(float2*)&dxp[((size_t)(bt0+r)*ED_ + c)*2] = make_float2(dv, at[c][r]);
    }
  } else if (c < 320){
    #pragma unroll
    for (int r=0;r<8;r++) bcf[((size_t)(bt0+r)*NS + (c-256))*2 + 0] = acc[r];
  } else {
    #pragma unroll
    for (int r=0;r<8;r++) bcf[((size_t)(bt0+r)*NS + (c-320))*2 + 1] = acc[r];
  }
}

// K5: chunked scan, 8 chunks of 128 per (b,e). One 512-thread block per (b,e);
// wave w owns chunk w. launch_bounds(512,8) -> 8 waves/SIMD (32/CU), VGPR cap 64.
// Phase 1 (waves 0..6): carry-only scan -> h_end, aprod = exp2(A2 * sum d).
// Combine via LDS (<=7 fma). Phase 2 (all): full output scan with fused-DPP reduce.
// Loads are packed: {d,xs} one dwordx2 (uniform), {B,C} one dwordx2 (coalesced).
__global__ __launch_bounds__(512,8) void k5_scan(const float* dxpf, const float* bcf,
                                                  const float* Alog, float* yraw){
  __shared__ float lcar[7][64];
  __shared__ float laprod[7][64];
  int i = blockIdx.x;
  int w = threadIdx.x >> 6;      // chunk index 0..7
  int n = threadIdx.x & 63;      // state index
  int x = i & 7;                 // XCD
  int r = i >> 3;                // 0..127
  int b = r & 3;
  int g = r >> 2;                // 0..31
  int e = x*32 + g;
  const int CH = T_SEQ/8;        // 128
  int t0 = w*CH;
  float A  = -__expf(Alog[e*NS+n]);
  float A2 = A * 1.44269504088896340736f;   // use exp2 directly
  const float2* pd  = (const float2*)dxpf + (size_t)(b*T_SEQ + t0)*ED_ + e;  // {d, xs}
  const float2* pbc = (const float2*)bcf  + (size_t)(b*T_SEQ + t0)*NS  + n;  // {B, C}
  float*        py  = yraw + (size_t)(b*T_SEQ + t0)*ED_ + e;
  bool last = (n==63);

  // ---- phase 1: carry-only scan (waves 0..6)
  if (w < 7){
    float h = 0.f, S = 0.f;
    float2 dA[4], dB[4]; float bA[4], bB[4];
    const float* pbx = (const float*)pbc;   // read only B (.x) as scalar
    #pragma unroll
    for (int j=0;j<4;j++){ dA[j]=pd[j*ED_]; bA[j]=pbx[j*NS*2]; }
    for (int t=0; t<CH; t+=8){
      #pragma unroll
      for (int j=0;j<4;j++){ int s=t+4+j; dB[j]=pd[s*ED_]; bB[j]=pbx[s*NS*2]; }
      #pragma unroll
      for (int j=0;j<4;j++){ float a=exp2_(dA[j].x*A2); h = fmaf(a,h,dA[j].x*dA[j].y*bA[j]); S += dA[j].x; }
      if (t+8 < CH){
        #pragma unroll
        for (int j=0;j<4;j++){ int s=t+8+j; dA[j]=pd[s*ED_]; bA[j]=pbx[s*NS*2]; }
      }
      #pragma unroll
      for (int j=0;j<4;j++){ float a=exp2_(dB[j].x*A2); h = fmaf(a,h,dB[j].x*dB[j].y*bB[j]); S += dB[j].x; }
    }
    lcar[w][n]   = h;
    laprod[w][n] = exp2_(A2*S);
  }
  __syncthreads();

  // ---- combine: h_in for this wave's chunk (scan of chunk carries 0..w-1)
  float hin = 0.f;
  if (w >= 1) hin = lcar[0][n];
  #pragma unroll
  for (int q=1;q<7;q++) if (w > q) hin = fmaf(laprod[q][n], hin, lcar[q][n]);

  // ---- phase 2: full output scan from hin
  {
    float h = hin;
    float2 dA[4], bA[4], dB[4], bB[4];
    #pragma unroll
    for (int j=0;j<4;j++){ dA[j]=pd[j*ED_]; bA[j]=pbc[j*NS]; }
    for (int t=0; t<CH; t+=8){
      // prefetch t+4..t+7 into B
      #pragma unroll
      for (int j=0;j<4;j++){ int s=t+4+j; dB[j]=pd[s*ED_]; bB[j]=pbc[s*NS]; }
      // compute batch A
      {
        float pp[4];
        #pragma unroll
        for (int j=0;j<4;j++){ float a=exp2_(dA[j].x*A2); h = fmaf(a,h,dA[j].x*dA[j].y*bA[j].x); pp[j] = h*bA[j].y; }
        #pragma unroll
        for (int j=0;j<4;j++) DPPR(pp[j], "row_shr:1");
        #pragma unroll
        for (int j=0;j<4;j++) DPPR(pp[j], "row_shr:2");
        #pragma unroll
        for (int j=0;j<4;j++) DPPR(pp[j], "row_shr:4");
        #pragma unroll
        for (int j=0;j<4;j++) DPPR(pp[j], "row_shr:8");
        #pragma unroll
        for (int j=0;j<4;j++) DPPR(pp[j], "row_bcast:15");
        #pragma unroll
        for (int j=0;j<4;j++) DPPR(pp[j], "row_bcast:31");
        if (last){
          #pragma unroll
          for (int j=0;j<4;j++) py[(t+j)*ED_] = pp[j];
        }
      }
      // prefetch t+8..t+11 into A
      if (t+8 < CH){
        #pragma unroll
        for (int j=0;j<4;j++){ int s=t+8+j; dA[j]=pd[s*ED_]; bA[j]=pbc[s*NS]; }
      }
      // compute batch B
      {
        float pp[4];
        #pragma unroll
        for (int j=0;j<4;j++){ float a=exp2_(dB[j].x*A2); h = fmaf(a,h,dB[j].x*dB[j].y*bB[j].x); pp[j] = h*bB[j].y; }
        #pragma unroll
        for (int j=0;j<4;j++) DPPR(pp[j], "row_shr:1");
        #pragma unroll
        for (int j=0;j<4;j++) DPPR(pp[j], "row_shr:2");
        #pragma unroll
        for (int j=0;j<4;j++) DPPR(pp[j], "row_shr:4");
        #pragma unroll
        for (int j=0;j<4;j++) DPPR(pp[j], "row_shr:8");
        #pragma unroll
        for (int j=0;j<4;j++) DPPR(pp[j], "row_bcast:15");
        #pragma unroll
        for (int j=0;j<4;j++) DPPR(pp[j], "row_bcast:31");
        if (last){
          #pragma unroll
          for (int j=0;j<4;j++) py[(t+4+j)*ED_] = pp[j];
        }
      }
    }
  }
}

// K6: y = (yraw + D*xs)*silu(zg);  out = LayerNorm(y @ out_proj_W.T + 2*z)*ln_w + ln_b
// xs now read from dxpack.y (stride-2 floats).
__global__ __launch_bounds__(256) void k6_out(const float* yraw, const float* dxpf, const float* zg,
                                               const float* Dp, const float* W, const float* z,
                                               const float* lnw, const float* lnb, float* out){
  __shared__ float yt[256][8];
  __shared__ float psum[4][4], psq[4][4];
  int bt0 = blockIdx.x*8; int tid = threadIdx.x;
  int d = tid & 127, gdx = tid>>7;
  for (int i=tid;i<2048;i+=256){
    int r=i>>8,k=i&255; int bt=bt0+r;
    float zgv = zg[bt*ED_ + k];
    float xsv = dxpf[((size_t)bt*ED_ + k)*2 + 1];
    float yv  = yraw[bt*ED_ + k] + Dp[k]*xsv;
    yt[k][r] = yv * zgv * sigmoidf_(zgv);
  }
  __syncthreads();
  float acc[4] = {0.f,0.f,0.f,0.f};
  for (int k=0;k<256;k+=4){
    float4 wv = *(const float4*)(W + d*256 + k);
    float w[4] = {wv.x, wv.y, wv.z, wv.w};
    #pragma unroll
    for (int kk=0;kk<4;kk++){
      float4 q = *(const float4*)&yt[k+kk][gdx*4];
      acc[0] = fmaf(q.x, w[kk], acc[0]);
      acc[1] = fmaf(q.y, w[kk], acc[1]);
      acc[2] = fmaf(q.z, w[kk], acc[2]);
      acc[3] = fmaf(q.w, w[kk], acc[3]);
    }
  }
  float val[4];
  #pragma unroll
  for (int j=0;j<4;j++){
    int bt = bt0 + gdx*4 + j;
    val[j] = acc[j] + 2.f*z[bt*DM + d];
  }
  int w_id = tid>>6;
  #pragma unroll
  for (int j=0;j<4;j++){
    float s = val[j], q = val[j]*val[j];
    #pragma unroll
    for (int off=32; off>=1; off>>=1){ s += __shfl_down(s, off); q += __shfl_down(q, off); }
    if ((tid&63)==0){ psum[w_id][j]=s; psq[w_id][j]=q; }
  }
  __syncthreads();
  float lw = lnw[d], lb = lnb[d];
  #pragma unroll
  for (int j=0;j<4;j++){
    int bt = bt0 + gdx*4 + j;
    float sum = psum[gdx*2][j] + psum[gdx*2+1][j];
    float sq  = psq [gdx*2][j] + psq [gdx*2+1][j];
    float mu  = sum*(1.f/DM);
    float var = sq*(1.f/DM) - mu*mu;
    float inv = rsqrtf(var + 1e-5f);
    out[bt*DM + d] = (val[j]-mu)*inv*lw + lb;
  }
}

extern "C" void kernel_launch(void* const* d_in, const int* in_sizes, int n_in,
                              void* d_out, int out_size, void* d_ws, size_t ws_size,
                              hipStream_t stream){
  const float* zseq = (const float*)d_in[0];
  const float* aux  = (const float*)d_in[1];
  const float* auxW = (const float*)d_in[2];
  const float* auxb = (const float*)d_in[3];
  const float* lnw  = (const float*)d_in[4];
  const float* lnb  = (const float*)d_in[5];
  const float* rmsw = (const float*)d_in[6];
  const float* inW  = (const float*)d_in[7];
  const float* convW= (const float*)d_in[8];
  const float* convb= (const float*)d_in[9];
  const float* xpW  = (const float*)d_in[10];
  const float* dtW  = (const float*)d_in[11];
  const float* dtb  = (const float*)d_in[12];
  const float* Alog = (const float*)d_in[13];
  const float* Dp   = (const float*)d_in[14];
  const float* outW = (const float*)d_in[15];
  float* out = (float*)d_out;
  float* ws = (float*)d_ws;

  float* z   = ws+OFF_Z;
  float* zg  = ws+OFF_ZG;
  float* xsr = ws+OFF_XSR;
  float* Wc  = ws+OFF_WC;
  float* yr  = ws+OFF_YR;
  float* dxp = ws+OFF_DPX;
  float* bcp = ws+OFF_BC;

  k2_fused <<<896,256,0,stream>>>(zseq,aux,auxW,auxb,rmsw,inW,xpW,dtW,z,xsr,zg,Wc);
  k4b_xproj<<<512,384,0,stream>>>(xsr,convW,convb,Wc,dtb,dxp,bcp);
  k5_scan  <<<1024,512,0,stream>>>(dxp,bcp,Alog,yr);
  k6_out   <<<512,256,0,stream>>>(yr,dxp,zg,Dp,outW,z,lnw,lnb,out);
}

// Round 3
// 246.571 us; speedup vs baseline: 1.1126x; 1.1126x over previous
//
#include <hip/hip_runtime.h>
#include <hip/hip_bf16.h>

#define B_SZ 4
#define T_SEQ 1024
#define DM 128
#define ED_ 256
#define NS 64
#define LOG2E 1.44269504088896340736f

// workspace layout (float elements). Total = 5,996,544 floats = 24.0 MB.
#define OFF_Z      0u         /* 524288  f32  z (residual, read by K6)            */
#define OFF_ZG     524288u    /* 1048576 f32  gate (k2 -> k6)                     */
#define OFF_XSR    1572864u   /* 1048576 f32  conv input (k2 -> k4b)              */
#define OFF_WC     2621440u   /* 98304   f32  combined x_proj/dt weight (384x256) */
#define OFF_YR     2719744u   /* 1048576 f32  raw scan output (k5 -> k6)          */
#define OFF_DPX    3768320u   /* 2097152 f32  {delta, xs} pairs (k4b -> k5,k6)    */
#define OFF_BC     5865472u   /* 131072  f32  {B, C} pairs (k4b -> k5)            */

__device__ __forceinline__ float sigmoidf_(float x){ return 1.f/(1.f+__expf(-x)); }
__device__ __forceinline__ float exp2_(float x){ return __builtin_amdgcn_exp2f(x); }

// Fused DPP add: p += dpp(p) in ONE instruction. bound_ctrl:0 => invalid lanes read 0.
#define DPPR(p, ctl) asm("v_add_f32_dpp %0, %0, %0 " ctl " row_mask:0xf bank_mask:0xf bound_ctrl:0" : "+v"(p))

// K2f: blocks 0..511: fused [z = zseq+aux@auxW.T+auxb ; zn=RMSNorm(z)*rms_w] -> LDS,
//      then xz = zn @ in_proj_W.T -> xsr | zg. blocks 512..895: build Wc.
__global__ __launch_bounds__(256) void k2_fused(const float* zseq, const float* aux, const float* auxW,
                                                const float* auxb, const float* rmsw, const float* W,
                                                const float* xprojW, const float* dtW,
                                                float* z, float* xsr, float* zg, float* Wc){
  if (blockIdx.x >= 512){
    int r = blockIdx.x - 512; int k = threadIdx.x;
    float v;
    if (r < 256){
      v = 0.f;
      #pragma unroll
      for (int j=0;j<8;j++) v += dtW[r*8+j] * xprojW[j*256+k];
    } else {
      v = xprojW[(8 + r-256)*256 + k];
    }
    Wc[r*256+k] = v;
    return;
  }
  __shared__ float at[128][8];
  int bt0 = blockIdx.x*8; int tid = threadIdx.x;
  {
    int r = tid>>5, l = tid&31;
    int bt = bt0 + r;
    float a0 = aux[bt*3+0], a1 = aux[bt*3+1], a2 = aux[bt*3+2];
    float zv[4]; float ssq = 0.f;
    #pragma unroll
    for (int j=0;j<4;j++){
      int d = l + 32*j;
      float v = zseq[bt*DM+d] + a0*auxW[d*3+0] + a1*auxW[d*3+1] + a2*auxW[d*3+2] + auxb[d];
      zv[j] = v; ssq += v*v;
    }
    #pragma unroll
    for (int m=16;m>=1;m>>=1) ssq += __shfl_xor(ssq, m);
    float rinv = rsqrtf(ssq*(1.f/DM) + 1e-5f);
    #pragma unroll
    for (int j=0;j<4;j++){
      int d = l + 32*j;
      z[bt*DM+d] = zv[j];
      at[d][r] = zv[j]*rinv*rmsw[d];
    }
  }
  __syncthreads();
  float acc0[8], acc1[8];
  #pragma unroll
  for (int r=0;r<8;r++){ acc0[r]=0.f; acc1[r]=0.f; }
  int c0 = tid, c1 = tid+256;
  for (int k=0;k<128;k+=4){
    float4 w0v = *(const float4*)(W + c0*128 + k);
    float4 w1v = *(const float4*)(W + c1*128 + k);
    float w0[4] = {w0v.x, w0v.y, w0v.z, w0v.w};
    float w1[4] = {w1v.x, w1v.y, w1v.z, w1v.w};
    #pragma unroll
    for (int kk=0;kk<4;kk++){
      float a[8];
      *(float4*)&a[0] = *(const float4*)&at[k+kk][0];
      *(float4*)&a[4] = *(const float4*)&at[k+kk][4];
      #pragma unroll
      for (int r=0;r<8;r++){ acc0[r] = fmaf(a[r], w0[kk], acc0[r]); acc1[r] = fmaf(a[r], w1[kk], acc1[r]); }
    }
  }
  #pragma unroll
  for (int r=0;r<8;r++){
    int bt = bt0+r;
    xsr[bt*ED_ + c0] = acc0[r];
    zg [bt*ED_ + c0] = acc1[r];
  }
}

// K4b: conv(k=4)+bias+SiLU from xsr (LDS), then [delta_pre | B | C] = xs @ Wc.T.
// Packed outputs: dxp[bt][e] = {softplus(delta_pre+dt_b), xs}; bcp[bt][n] = {B, C}.
__global__ __launch_bounds__(384) void k4b_xproj(const float* xsr, const float* convW, const float* convb,
                                                 const float* Wc, const float* dtb,
                                                 float* dxp, float* bcf){
  __shared__ float at[256][8];
  int bt0 = blockIdx.x*8; int tid = threadIdx.x;
  for (int i=tid;i<2048;i+=384){
    int r=i>>8,k=i&255; int bt=bt0+r; int t = bt & (T_SEQ-1);
    float4 wv = *(const float4*)(convW + k*4);
    float s = convb[k];
    if (t>=3) s += xsr[(bt-3)*ED_+k]*wv.x;
    if (t>=2) s += xsr[(bt-2)*ED_+k]*wv.y;
    if (t>=1) s += xsr[(bt-1)*ED_+k]*wv.z;
    s += xsr[bt*ED_+k]*wv.w;
    at[k][r] = s * sigmoidf_(s);
  }
  __syncthreads();
  float acc[8];
  #pragma unroll
  for (int r=0;r<8;r++) acc[r]=0.f;
  int c = tid;
  for (int k=0;k<256;k+=4){
    float4 wv = *(const float4*)(Wc + c*256 + k);
    float w[4] = {wv.x, wv.y, wv.z, wv.w};
    #pragma unroll
    for (int kk=0;kk<4;kk++){
      float a[8];
      *(float4*)&a[0] = *(const float4*)&at[k+kk][0];
      *(float4*)&a[4] = *(const float4*)&at[k+kk][4];
      #pragma unroll
      for (int r=0;r<8;r++) acc[r] = fmaf(a[r], w[kk], acc[r]);
    }
  }
  if (c < 256){
    float bc = dtb[c];
    #pragma unroll
    for (int r=0;r<8;r++){
      float x = acc[r] + bc;
      float dv = (x > 20.f) ? x : log1pf(__expf(x));
      *(float2*)&dxp[((size_t)(bt0+r)*ED_ + c)*2] = make_float2(dv, at[c][r]);
    }
  } else if (c < 320){
    #pragma unroll
    for (int r=0;r<8;r++) bcf[((size_t)(bt0+r)*NS + (c-256))*2 + 0] = acc[r];
  } else {
    #pragma unroll
    for (int r=0;r<8;r++) bcf[((size_t)(bt0+r)*NS + (c-320))*2 + 1] = acc[r];
  }
}

// K5: chunked scan, 2 STATES PER LANE + 2 e's PER WAVE.
//   lanes 0-31: e_even (states nl, nl+32 per lane), lanes 32-63: e_odd.
//   B/C are shared across e, so both halves load identical bc words.
//   8 chunks of 128; block = 8 waves (512 thr), grid 512 = 2 blocks/CU exactly.
//   launch_bounds(512,4): VGPR cap 128 (R2's (512,8) cap-64 collapsed the
//   prefetch to VGPR=24 and serialized every load -- never again).
//   Phase 1 (waves 0..6): carry-only scan -> {h_lo, h_hi, S=sum delta} in LDS.
//   Combine: hin = prefix-fold with decay exp2(A2*S_q) recomputed per state.
//   Phase 2: output scan, depth-8 double-buffered loads, 5-step DPP 32-lane
//   reduce (totals land in lanes 31 and 63 = one predicated store, 2 e's).
__global__ __launch_bounds__(512,4) void k5_scan(const float* dxpf, const float* bcf,
                                                  const float* Alog, float* yraw){
  __shared__ float lcL[7][64], lcH[7][64], lS[7][64];
  int i  = blockIdx.x;
  int w  = threadIdx.x >> 6;     // chunk 0..7
  int ln = threadIdx.x & 63;
  int nl = ln & 31;              // low state index
  int half = ln >> 5;            // which e of the pair
  int x = i & 7;                 // XCD
  int r = i >> 3;                // 0..63
  int b = r & 3;
  int g = r >> 2;                // e-pair 0..15 within XCD slice
  int e = x*32 + g*2 + half;
  const int CH = T_SEQ/8;        // 128
  int t0 = w*CH;
  float A2a = -__expf(Alog[e*NS + nl])      * LOG2E;
  float A2b = -__expf(Alog[e*NS + nl + 32]) * LOG2E;
  const float2* pd  = (const float2*)dxpf + (size_t)(b*T_SEQ + t0)*ED_ + e;   // {delta, xs}
  const float2* pb0 = (const float2*)bcf  + (size_t)(b*T_SEQ + t0)*NS  + nl;  // {B,C}[nl]
  float* py = yraw + (size_t)(b*T_SEQ + t0)*ED_ + e;
  bool last = (nl == 31);

  // ---- phase 1: carry-only scan (waves 0..6; wave 7's carry unused)
  if (w < 7){
    float h0=0.f, h1=0.f, S=0.f;
    float2 dA[8], dB[8];
    float bA0[8], bA1[8], bB0[8], bB1[8];
    #pragma unroll
    for (int j=0;j<8;j++){ dA[j]=pd[j*ED_]; bA0[j]=pb0[j*NS].x; bA1[j]=pb0[j*NS+32].x; }
    for (int t=0; t<CH; t+=16){
      #pragma unroll
      for (int j=0;j<8;j++){ int s=t+8+j; dB[j]=pd[s*ED_]; bB0[j]=pb0[s*NS].x; bB1[j]=pb0[s*NS+32].x; }
      #pragma unroll
      for (int j=0;j<8;j++){
        float a0=exp2_(dA[j].x*A2a), a1=exp2_(dA[j].x*A2b);
        float u = dA[j].x*dA[j].y;
        h0=fmaf(a0,h0,u*bA0[j]); h1=fmaf(a1,h1,u*bA1[j]); S+=dA[j].x;
      }
      if (t+16 < CH){
        #pragma unroll
        for (int j=0;j<8;j++){ int s=t+16+j; dA[j]=pd[s*ED_]; bA0[j]=pb0[s*NS].x; bA1[j]=pb0[s*NS+32].x; }
      }
      #pragma unroll
      for (int j=0;j<8;j++){
        float a0=exp2_(dB[j].x*A2a), a1=exp2_(dB[j].x*A2b);
        float u = dB[j].x*dB[j].y;
        h0=fmaf(a0,h0,u*bB0[j]); h1=fmaf(a1,h1,u*bB1[j]); S+=dB[j].x;
      }
    }
    lcL[w][ln]=h0; lcH[w][ln]=h1; lS[w][ln]=S;
  }
  __syncthreads();

  // ---- combine: fold carries of chunks < w (decay = exp2(A2 * S_q))
  float h0=0.f, h1=0.f;
  #pragma unroll
  for (int q=0;q<7;q++) if (w > q){
    float s = lS[q][ln];
    h0 = fmaf(exp2_(A2a*s), h0, lcL[q][ln]);
    h1 = fmaf(exp2_(A2b*s), h1, lcH[q][ln]);
  }

  // ---- phase 2: full output scan, depth-8 double-buffered
  {
    float2 dA[8], cA0[8], cA1[8], dB[8], cB0[8], cB1[8];
    #pragma unroll
    for (int j=0;j<8;j++){ dA[j]=pd[j*ED_]; cA0[j]=pb0[j*NS]; cA1[j]=pb0[j*NS+32]; }
    for (int t=0; t<CH; t+=16){
      #pragma unroll
      for (int j=0;j<8;j++){ int s=t+8+j; dB[j]=pd[s*ED_]; cB0[j]=pb0[s*NS]; cB1[j]=pb0[s*NS+32]; }
      // batch A
      {
        float pp[8];
        #pragma unroll
        for (int j=0;j<8;j++){
          float a0=exp2_(dA[j].x*A2a), a1=exp2_(dA[j].x*A2b);
          float u = dA[j].x*dA[j].y;
          h0=fmaf(a0,h0,u*cA0[j].x); h1=fmaf(a1,h1,u*cA1[j].x);
          pp[j]=fmaf(h1,cA1[j].y,h0*cA0[j].y);
        }
        #pragma unroll
        for (int j=0;j<8;j++) DPPR(pp[j], "row_shr:1");
        #pragma unroll
        for (int j=0;j<8;j++) DPPR(pp[j], "row_shr:2");
        #pragma unroll
        for (int j=0;j<8;j++) DPPR(pp[j], "row_shr:4");
        #pragma unroll
        for (int j=0;j<8;j++) DPPR(pp[j], "row_shr:8");
        #pragma unroll
        for (int j=0;j<8;j++) DPPR(pp[j], "row_bcast:15");
        if (last){
          #pragma unroll
          for (int j=0;j<8;j++) py[(t+j)*ED_] = pp[j];
        }
      }
      if (t+16 < CH){
        #pragma unroll
        for (int j=0;j<8;j++){ int s=t+16+j; dA[j]=pd[s*ED_]; cA0[j]=pb0[s*NS]; cA1[j]=pb0[s*NS+32]; }
      }
      // batch B
      {
        float pp[8];
        #pragma unroll
        for (int j=0;j<8;j++){
          float a0=exp2_(dB[j].x*A2a), a1=exp2_(dB[j].x*A2b);
          float u = dB[j].x*dB[j].y;
          h0=fmaf(a0,h0,u*cB0[j].x); h1=fmaf(a1,h1,u*cB1[j].x);
          pp[j]=fmaf(h1,cB1[j].y,h0*cB0[j].y);
        }
        #pragma unroll
        for (int j=0;j<8;j++) DPPR(pp[j], "row_shr:1");
        #pragma unroll
        for (int j=0;j<8;j++) DPPR(pp[j], "row_shr:2");
        #pragma unroll
        for (int j=0;j<8;j++) DPPR(pp[j], "row_shr:4");
        #pragma unroll
        for (int j=0;j<8;j++) DPPR(pp[j], "row_shr:8");
        #pragma unroll
        for (int j=0;j<8;j++) DPPR(pp[j], "row_bcast:15");
        if (last){
          #pragma unroll
          for (int j=0;j<8;j++) py[(t+8+j)*ED_] = pp[j];
        }
      }
    }
  }
}

// K6: y = (yraw + D*xs)*silu(zg);  out = LayerNorm(y @ out_proj_W.T + 2*z)*ln_w + ln_b
__global__ __launch_bounds__(256) void k6_out(const float* yraw, const float* dxpf, const float* zg,
                                               const float* Dp, const float* W, const float* z,
                                               const float* lnw, const float* lnb, float* out){
  __shared__ float yt[256][8];
  __shared__ float psum[4][4], psq[4][4];
  int bt0 = blockIdx.x*8; int tid = threadIdx.x;
  int d = tid & 127, gdx = tid>>7;
  for (int i=tid;i<2048;i+=256){
    int r=i>>8,k=i&255; int bt=bt0+r;
    float zgv = zg[bt*ED_ + k];
    float xsv = dxpf[((size_t)bt*ED_ + k)*2 + 1];
    float yv  = yraw[bt*ED_ + k] + Dp[k]*xsv;
    yt[k][r] = yv * zgv * sigmoidf_(zgv);
  }
  __syncthreads();
  float acc[4] = {0.f,0.f,0.f,0.f};
  for (int k=0;k<256;k+=4){
    float4 wv = *(const float4*)(W + d*256 + k);
    float w[4] = {wv.x, wv.y, wv.z, wv.w};
    #pragma unroll
    for (int kk=0;kk<4;kk++){
      float4 q = *(const float4*)&yt[k+kk][gdx*4];
      acc[0] = fmaf(q.x, w[kk], acc[0]);
      acc[1] = fmaf(q.y, w[kk], acc[1]);
      acc[2] = fmaf(q.z, w[kk], acc[2]);
      acc[3] = fmaf(q.w, w[kk], acc[3]);
    }
  }
  float val[4];
  #pragma unroll
  for (int j=0;j<4;j++){
    int bt = bt0 + gdx*4 + j;
    val[j] = acc[j] + 2.f*z[bt*DM + d];
  }
  int w_id = tid>>6;
  #pragma unroll
  for (int j=0;j<4;j++){
    float s = val[j], q = val[j]*val[j];
    #pragma unroll
    for (int off=32; off>=1; off>>=1){ s += __shfl_down(s, off); q += __shfl_down(q, off); }
    if ((tid&63)==0){ psum[w_id][j]=s; psq[w_id][j]=q; }
  }
  __syncthreads();
  float lw = lnw[d], lb = lnb[d];
  #pragma unroll
  for (int j=0;j<4;j++){
    int bt = bt0 + gdx*4 + j;
    float sum = psum[gdx*2][j] + psum[gdx*2+1][j];
    float sq  = psq [gdx*2][j] + psq [gdx*2+1][j];
    float mu  = sum*(1.f/DM);
    float var = sq*(1.f/DM) - mu*mu;
    float inv = rsqrtf(var + 1e-5f);
    out[bt*DM + d] = (val[j]-mu)*inv*lw + lb;
  }
}

extern "C" void kernel_launch(void* const* d_in, const int* in_sizes, int n_in,
                              void* d_out, int out_size, void* d_ws, size_t ws_size,
                              hipStream_t stream){
  const float* zseq = (const float*)d_in[0];
  const float* aux  = (const float*)d_in[1];
  const float* auxW = (const float*)d_in[2];
  const float* auxb = (const float*)d_in[3];
  const float* lnw  = (const float*)d_in[4];
  const float* lnb  = (const float*)d_in[5];
  const float* rmsw = (const float*)d_in[6];
  const float* inW  = (const float*)d_in[7];
  const float* convW= (const float*)d_in[8];
  const float* convb= (const float*)d_in[9];
  const float* xpW  = (const float*)d_in[10];
  const float* dtW  = (const float*)d_in[11];
  const float* dtb  = (const float*)d_in[12];
  const float* Alog = (const float*)d_in[13];
  const float* Dp   = (const float*)d_in[14];
  const float* outW = (const float*)d_in[15];
  float* out = (float*)d_out;
  float* ws = (float*)d_ws;

  float* z   = ws+OFF_Z;
  float* zg  = ws+OFF_ZG;
  float* xsr = ws+OFF_XSR;
  float* Wc  = ws+OFF_WC;
  float* yr  = ws+OFF_YR;
  float* dxp = ws+OFF_DPX;
  float* bcp = ws+OFF_BC;

  k2_fused <<<896,256,0,stream>>>(zseq,aux,auxW,auxb,rmsw,inW,xpW,dtW,z,xsr,zg,Wc);
  k4b_xproj<<<512,384,0,stream>>>(xsr,convW,convb,Wc,dtb,dxp,bcp);
  k5_scan  <<<512,512,0,stream>>>(dxp,bcp,Alog,yr);
  k6_out   <<<512,256,0,stream>>>(yr,dxp,zg,Dp,outW,z,lnw,lnb,out);
}

// Round 6
// 220.606 us; speedup vs baseline: 1.2436x; 1.1177x over previous
//
#include <hip/hip_runtime.h>
#include <hip/hip_bf16.h>

#define B_SZ 4
#define T_SEQ 1024
#define DM 128
#define ED_ 256
#define NS 64
#define LOG2E 1.44269504088896340736f

// workspace layout (float elements). Total = 6,389,760 floats = 25.6 MB (accepted size).
// dxpT is TRANSPOSED [b][e][t] x {delta, delta*xs}; yrT is TRANSPOSED [b][e][t].
#define OFF_Z      0u         /* 524288  f32  z (residual, read by K6)            */
#define OFF_ZG     524288u    /* 1048576 f32  gate (k2 -> k6)                     */
#define OFF_XSR    1572864u   /* 1048576 f32  conv input (k2 -> k4b)              */
#define OFF_WC     2621440u   /* 98304   f32  combined x_proj/dt weight (384x256) */
#define OFF_YR     2719744u   /* 1048576 f32  scan output, [b][e][t] (k5 -> k6)   */
#define OFF_DPX    3768320u   /* 2097152 f32  {delta, delta*xs} [b][e][t] pairs   */
#define OFF_BC     5865472u   /* 524288  f32  {B, C} [b][t][n] pairs (k4b -> k5)  */

__device__ __forceinline__ float sigmoidf_(float x){ return 1.f/(1.f+__expf(-x)); }
__device__ __forceinline__ float exp2_(float x){ return __builtin_amdgcn_exp2f(x); }
__device__ __forceinline__ float rlane_(float v, int l){
  return __int_as_float(__builtin_amdgcn_readlane(__float_as_int(v), l));
}
// collect: accI[lane t] = total of pp (total sits in lane 63 after DPP6).
// v_writelane may read only ONE SGPR (constant-bus rule) -> lane select must be
// an IMMEDIATE. All call sites pass t = unrolled-loop constant, so "i" folds.
__device__ __forceinline__ void collect_(int &accI, float pp, int t){
  int s;
  asm("v_readlane_b32 %0, %1, 63" : "=s"(s) : "v"(__float_as_int(pp)));
  asm("v_writelane_b32 %0, %1, %2" : "+v"(accI) : "s"(s), "i"(t));
}

// Fused DPP add: p += dpp(p) in ONE instruction. bound_ctrl:0 => invalid lanes read 0.
#define DPPR(p, ctl) asm("v_add_f32_dpp %0, %0, %0 " ctl " row_mask:0xf bank_mask:0xf bound_ctrl:0" : "+v"(p))
#define DPP6(p) do{ DPPR(p,"row_shr:1"); DPPR(p,"row_shr:2"); DPPR(p,"row_shr:4"); \
                    DPPR(p,"row_shr:8"); DPPR(p,"row_bcast:15"); DPPR(p,"row_bcast:31"); }while(0)

// K2f: blocks 0..511: fused [z = zseq+aux@auxW.T+auxb ; zn=RMSNorm(z)*rms_w] -> LDS,
//      then xz = zn @ in_proj_W.T -> xsr | zg. blocks 512..895: build Wc.
__global__ __launch_bounds__(256) void k2_fused(const float* zseq, const float* aux, const float* auxW,
                                                const float* auxb, const float* rmsw, const float* W,
                                                const float* xprojW, const float* dtW,
                                                float* z, float* xsr, float* zg, float* Wc){
  if (blockIdx.x >= 512){
    int r = blockIdx.x - 512; int k = threadIdx.x;
    float v;
    if (r < 256){
      v = 0.f;
      #pragma unroll
      for (int j=0;j<8;j++) v += dtW[r*8+j] * xprojW[j*256+k];
    } else {
      v = xprojW[(8 + r-256)*256 + k];
    }
    Wc[r*256+k] = v;
    return;
  }
  __shared__ float at[128][8];
  int bt0 = blockIdx.x*8; int tid = threadIdx.x;
  {
    int r = tid>>5, l = tid&31;
    int bt = bt0 + r;
    float a0 = aux[bt*3+0], a1 = aux[bt*3+1], a2 = aux[bt*3+2];
    float zv[4]; float ssq = 0.f;
    #pragma unroll
    for (int j=0;j<4;j++){
      int d = l + 32*j;
      float v = zseq[bt*DM+d] + a0*auxW[d*3+0] + a1*auxW[d*3+1] + a2*auxW[d*3+2] + auxb[d];
      zv[j] = v; ssq += v*v;
    }
    #pragma unroll
    for (int m=16;m>=1;m>>=1) ssq += __shfl_xor(ssq, m);
    float rinv = rsqrtf(ssq*(1.f/DM) + 1e-5f);
    #pragma unroll
    for (int j=0;j<4;j++){
      int d = l + 32*j;
      z[bt*DM+d] = zv[j];
      at[d][r] = zv[j]*rinv*rmsw[d];
    }
  }
  __syncthreads();
  float acc0[8], acc1[8];
  #pragma unroll
  for (int r=0;r<8;r++){ acc0[r]=0.f; acc1[r]=0.f; }
  int c0 = tid, c1 = tid+256;
  for (int k=0;k<128;k+=4){
    float4 w0v = *(const float4*)(W + c0*128 + k);
    float4 w1v = *(const float4*)(W + c1*128 + k);
    float w0[4] = {w0v.x, w0v.y, w0v.z, w0v.w};
    float w1[4] = {w1v.x, w1v.y, w1v.z, w1v.w};
    #pragma unroll
    for (int kk=0;kk<4;kk++){
      float a[8];
      *(float4*)&a[0] = *(const float4*)&at[k+kk][0];
      *(float4*)&a[4] = *(const float4*)&at[k+kk][4];
      #pragma unroll
      for (int r=0;r<8;r++){ acc0[r] = fmaf(a[r], w0[kk], acc0[r]); acc1[r] = fmaf(a[r], w1[kk], acc1[r]); }
    }
  }
  #pragma unroll
  for (int r=0;r<8;r++){
    int bt = bt0+r;
    xsr[bt*ED_ + c0] = acc0[r];
    zg [bt*ED_ + c0] = acc1[r];
  }
}

// K4b: conv(k=4)+bias+SiLU from xsr (LDS), then [delta_pre | B | C] = xs @ Wc.T.
// Outputs: dxpT[b][e][t] = {delta, delta*xs} (transposed, 64B/thread segments);
//          bcp[b][t][n]  = {B, C}.
__global__ __launch_bounds__(384) void k4b_xproj(const float* xsr, const float* convW, const float* convb,
                                                 const float* Wc, const float* dtb,
                                                 float* dxp, float* bcf){
  __shared__ float at[256][8];
  int bt0 = blockIdx.x*8; int tid = threadIdx.x;
  for (int i=tid;i<2048;i+=384){
    int r=i>>8,k=i&255; int bt=bt0+r; int t = bt & (T_SEQ-1);
    float4 wv = *(const float4*)(convW + k*4);
    float s = convb[k];
    if (t>=3) s += xsr[(bt-3)*ED_+k]*wv.x;
    if (t>=2) s += xsr[(bt-2)*ED_+k]*wv.y;
    if (t>=1) s += xsr[(bt-1)*ED_+k]*wv.z;
    s += xsr[bt*ED_+k]*wv.w;
    at[k][r] = s * sigmoidf_(s);
  }
  __syncthreads();
  float acc[8];
  #pragma unroll
  for (int r=0;r<8;r++) acc[r]=0.f;
  int c = tid;
  for (int k=0;k<256;k+=4){
    float4 wv = *(const float4*)(Wc + c*256 + k);
    float w[4] = {wv.x, wv.y, wv.z, wv.w};
    #pragma unroll
    for (int kk=0;kk<4;kk++){
      float a[8];
      *(float4*)&a[0] = *(const float4*)&at[k+kk][0];
      *(float4*)&a[4] = *(const float4*)&at[k+kk][4];
      #pragma unroll
      for (int r=0;r<8;r++) acc[r] = fmaf(a[r], w[kk], acc[r]);
    }
  }
  int b4 = bt0 >> 10, tb = bt0 & (T_SEQ-1);
  if (c < 256){
    float bcv = dtb[c];
    float2* pout = (float2*)dxp + (size_t)(b4*ED_ + c)*T_SEQ + tb;
    #pragma unroll
    for (int r=0;r<8;r++){
      float xv = acc[r] + bcv;
      float dv = (xv > 20.f) ? xv : log1pf(__expf(xv));
      pout[r] = make_float2(dv, dv * at[c][r]);   // {delta, delta*xs}
    }
  } else if (c < 320){
    #pragma unroll
    for (int r=0;r<8;r++) bcf[((size_t)(bt0+r)*NS + (c-256))*2 + 0] = acc[r];
  } else {
    #pragma unroll
    for (int r=0;r<8;r++) bcf[((size_t)(bt0+r)*NS + (c-320))*2 + 1] = acc[r];
  }
}

// K5: chunked scan, R1 structure (4 chunks x 256 t, 256-thr block per (b,e),
// grid 1024 = 4 blocks/CU, launch_bounds(256,4) -> VGPR cap 128).
// vs R1 (kills ~2/3 of per-t instructions; R0-R3 showed ~37 instr/t,
// mostly 64-bit addressing + 4 VMEM streams + DPP pairs):
//  - dxpT[b][e][t]{delta,u=delta*xs} is wave-uniform -> lane=t: ONE dwordx2
//    load covers 64 timesteps; per-t broadcast via v_readlane (SGPR operand).
//  - y collected via readlane(pp,63)+writelane(acc,imm t): one coalesced 256B
//    store per 64 t to yrT[b][e][t]; no predicated stores, zero divergence.
//  - bc {B,C} packed: one dwordx2/t, imm offsets cover 8 t per base bump.
//  - chunk decay: Sum(delta) over 64 t = one DPP reduce of the lane=t reg.
__global__ __launch_bounds__(256,4) void k5_scan(const float* dxpf, const float* bcf,
                                                  const float* Alog, float* yrT){
  __shared__ float lcar[3][64], lapr[3][64];
  int i = blockIdx.x;
  int w = threadIdx.x >> 6;      // chunk 0..3
  int n = threadIdx.x & 63;      // state index (lane)
  int x = i & 7;                 // XCD swizzle
  int r = i >> 3;
  int b = r & 3;
  int g = r >> 2;                // 0..31
  int e = x*32 + g;
  const int CH = T_SEQ/4;        // 256
  int t0 = w*CH;
  float A2 = -__expf(Alog[e*NS+n]) * LOG2E;
  const float2* pd  = (const float2*)dxpf + (size_t)(b*ED_ + e)*T_SEQ + t0;  // lane=t
  const float2* pbc = (const float2*)bcf  + (size_t)(b*T_SEQ + t0)*NS + n;   // lane=n
  float*        py  = yrT + (size_t)(b*ED_ + e)*T_SEQ + t0;

  // ---- phase 1: carry-only scan (waves 0..2)
  if (w < 3){
    float h = 0.f, Ssum = 0.f;
    float2 dxc = pd[n];
    for (int sb=0; sb<CH; sb+=64){
      float2 dxn = dxc;
      if (sb+64 < CH) dxn = pd[sb+64+n];
      float sv = dxc.x;
      DPP6(sv);
      Ssum += rlane_(sv, 63);
      float bA[8], bB[8];
      #pragma unroll
      for (int j=0;j<8;j++) bA[j] = pbc[(sb+j)*NS].x;
      #pragma unroll
      for (int bb=0; bb<64; bb+=16){
        #pragma unroll
        for (int j=0;j<8;j++) bB[j] = pbc[(sb+bb+8+j)*NS].x;
        #pragma unroll
        for (int j=0;j<8;j++){
          float sd = rlane_(dxc.x, bb+j);
          float su = rlane_(dxc.y, bb+j);
          h = fmaf(exp2_(sd*A2), h, su*bA[j]);
        }
        if (bb+16 < 64){
          #pragma unroll
          for (int j=0;j<8;j++) bA[j] = pbc[(sb+bb+16+j)*NS].x;
        }
        #pragma unroll
        for (int j=0;j<8;j++){
          float sd = rlane_(dxc.x, bb+8+j);
          float su = rlane_(dxc.y, bb+8+j);
          h = fmaf(exp2_(sd*A2), h, su*bB[j]);
        }
      }
      dxc = dxn;
    }
    lcar[w][n] = h;
    lapr[w][n] = exp2_(A2*Ssum);
  }
  __syncthreads();

  // ---- combine: h_in for this wave's chunk
  float h = 0.f;
  if (w >= 1) h = lcar[0][n];
  if (w >= 2) h = fmaf(lapr[1][n], h, lcar[1][n]);
  if (w >= 3) h = fmaf(lapr[2][n], h, lcar[2][n]);

  // ---- phase 2: full output scan
  {
    float2 dxc = pd[n];
    for (int sb=0; sb<CH; sb+=64){
      float2 dxn = dxc;
      if (sb+64 < CH) dxn = pd[sb+64+n];
      int accI = 0;
      float2 cA[8], cB[8];
      #pragma unroll
      for (int j=0;j<8;j++) cA[j] = pbc[(sb+j)*NS];
      #pragma unroll
      for (int bb=0; bb<64; bb+=16){
        #pragma unroll
        for (int j=0;j<8;j++) cB[j] = pbc[(sb+bb+8+j)*NS];
        #pragma unroll
        for (int j=0;j<8;j++){
          float sd = rlane_(dxc.x, bb+j);
          float su = rlane_(dxc.y, bb+j);
          h = fmaf(exp2_(sd*A2), h, su*cA[j].x);
          float pp = h*cA[j].y;
          DPP6(pp);
          collect_(accI, pp, bb+j);
        }
        if (bb+16 < 64){
          #pragma unroll
          for (int j=0;j<8;j++) cA[j] = pbc[(sb+bb+16+j)*NS];
        }
        #pragma unroll
        for (int j=0;j<8;j++){
          float sd = rlane_(dxc.x, bb+8+j);
          float su = rlane_(dxc.y, bb+8+j);
          h = fmaf(exp2_(sd*A2), h, su*cB[j].x);
          float pp = h*cB[j].y;
          DPP6(pp);
          collect_(accI, pp, bb+8+j);
        }
      }
      py[sb+n] = __int_as_float(accI);
      dxc = dxn;
    }
  }
}

// K6: stage yrT (e-major) + xs = u/delta from dxpT via LDS; combine with gate;
// then out = LayerNorm(y @ out_proj_W.T + 2*z)*ln_w + ln_b.
__global__ __launch_bounds__(256) void k6_out(const float* yrT, const float* dxpf, const float* zg,
                                               const float* Dp, const float* W, const float* z,
                                               const float* lnw, const float* lnb, float* out){
  __shared__ float yt[256][8];
  __shared__ float xst[256][8];
  __shared__ float psum[4][4], psq[4][4];
  int bt0 = blockIdx.x*8; int tid = threadIdx.x;
  int b4 = bt0 >> 10, tb = bt0 & (T_SEQ-1);
  int el = tid>>3, tl = tid&7;
  #pragma unroll
  for (int gg=0; gg<8; gg++){
    int ee = el + gg*32;
    size_t base = (size_t)(b4*ED_ + ee)*T_SEQ + tb + tl;
    float2 du = ((const float2*)dxpf)[base];
    yt[ee][tl]  = yrT[base];
    xst[ee][tl] = du.y / du.x;        // xs = (delta*xs)/delta; delta >= softplus(-4) ~ 0.018
  }
  __syncthreads();
  for (int i=tid;i<2048;i+=256){
    int rr=i>>8, k=i&255; int bt=bt0+rr;
    float zgv = zg[bt*ED_ + k];
    float yv  = yt[k][rr] + Dp[k]*xst[k][rr];
    yt[k][rr] = yv * zgv * sigmoidf_(zgv);
  }
  __syncthreads();
  int d = tid & 127, gdx = tid>>7;
  float acc[4] = {0.f,0.f,0.f,0.f};
  for (int k=0;k<256;k+=4){
    float4 wv = *(const float4*)(W + d*256 + k);
    float w[4] = {wv.x, wv.y, wv.z, wv.w};
    #pragma unroll
    for (int kk=0;kk<4;kk++){
      float4 q = *(const float4*)&yt[k+kk][gdx*4];
      acc[0] = fmaf(q.x, w[kk], acc[0]);
      acc[1] = fmaf(q.y, w[kk], acc[1]);
      acc[2] = fmaf(q.z, w[kk], acc[2]);
      acc[3] = fmaf(q.w, w[kk], acc[3]);
    }
  }
  float val[4];
  #pragma unroll
  for (int j=0;j<4;j++){
    int bt = bt0 + gdx*4 + j;
    val[j] = acc[j] + 2.f*z[bt*DM + d];
  }
  int w_id = tid>>6;
  #pragma unroll
  for (int j=0;j<4;j++){
    float s = val[j], q = val[j]*val[j];
    #pragma unroll
    for (int off=32; off>=1; off>>=1){ s += __shfl_down(s, off); q += __shfl_down(q, off); }
    if ((tid&63)==0){ psum[w_id][j]=s; psq[w_id][j]=q; }
  }
  __syncthreads();
  float lw = lnw[d], lb = lnb[d];
  #pragma unroll
  for (int j=0;j<4;j++){
    int bt = bt0 + gdx*4 + j;
    float sum = psum[gdx*2][j] + psum[gdx*2+1][j];
    float sq  = psq [gdx*2][j] + psq [gdx*2+1][j];
    float mu  = sum*(1.f/DM);
    float var = sq*(1.f/DM) - mu*mu;
    float inv = rsqrtf(var + 1e-5f);
    out[bt*DM + d] = (val[j]-mu)*inv*lw + lb;
  }
}

extern "C" void kernel_launch(void* const* d_in, const int* in_sizes, int n_in,
                              void* d_out, int out_size, void* d_ws, size_t ws_size,
                              hipStream_t stream){
  const float* zseq = (const float*)d_in[0];
  const float* aux  = (const float*)d_in[1];
  const float* auxW = (const float*)d_in[2];
  const float* auxb = (const float*)d_in[3];
  const float* lnw  = (const float*)d_in[4];
  const float* lnb  = (const float*)d_in[5];
  const float* rmsw = (const float*)d_in[6];
  const float* inW  = (const float*)d_in[7];
  const float* convW= (const float*)d_in[8];
  const float* convb= (const float*)d_in[9];
  const float* xpW  = (const float*)d_in[10];
  const float* dtW  = (const float*)d_in[11];
  const float* dtb  = (const float*)d_in[12];
  const float* Alog = (const float*)d_in[13];
  const float* Dp   = (const float*)d_in[14];
  const float* outW = (const float*)d_in[15];
  float* out = (float*)d_out;
  float* ws = (float*)d_ws;

  float* z   = ws+OFF_Z;
  float* zg  = ws+OFF_ZG;
  float* xsr = ws+OFF_XSR;
  float* Wc  = ws+OFF_WC;
  float* yr  = ws+OFF_YR;
  float* dxp = ws+OFF_DPX;
  float* bcp = ws+OFF_BC;

  k2_fused <<<896,256,0,stream>>>(zseq,aux,auxW,auxb,rmsw,inW,xpW,dtW,z,xsr,zg,Wc);
  k4b_xproj<<<512,384,0,stream>>>(xsr,convW,convb,Wc,dtb,dxp,bcp);
  k5_scan  <<<1024,256,0,stream>>>(dxp,bcp,Alog,yr);
  k6_out   <<<512,256,0,stream>>>(yr,dxp,zg,Dp,outW,z,lnw,lnb,out);
}